// Round 2
// baseline (285.428 us; speedup 1.0000x reference)
//
#include <hip/hip_runtime.h>
#include <stdint.h>
#include <stddef.h>

// Problem constants (from reference)
constexpr int kNodes = 50000;
constexpr int kEdges = 500000;
constexpr int kD     = 128;   // per-half feature dim
constexpr int kC     = 64;    // out classes
constexpr int kK     = 256;   // total K = 2*kD

typedef __attribute__((ext_vector_type(8))) short  short8;   // 8 x bf16 (4 VGPRs)
typedef __attribute__((ext_vector_type(4))) float  floatx4;  // MFMA C/D

// fp32 -> bf16, round-to-nearest-even
__device__ __forceinline__ unsigned short f2bf(float f) {
  union { float f; unsigned u; } v; v.f = f;
  unsigned u = v.u;
  unsigned r = u + 0x7FFFu + ((u >> 16) & 1u);
  return (unsigned short)(r >> 16);
}

__device__ __forceinline__ short8 cvt8(float4 a, float4 b) {
  short8 r;
  r[0] = (short)f2bf(a.x); r[1] = (short)f2bf(a.y);
  r[2] = (short)f2bf(a.z); r[3] = (short)f2bf(a.w);
  r[4] = (short)f2bf(b.x); r[5] = (short)f2bf(b.y);
  r[6] = (short)f2bf(b.z); r[7] = (short)f2bf(b.w);
  return r;
}

// Prep kernel: blocks [0,1024) convert h -> bf16; blocks [1024,1032) build the
// pre-swizzled bf16 W-fragment table (2048 fragments x 16B = 32 KiB).
// Fragment s = (kstep*4 + ntile)*64 + lane holds
//   W[ntile*16 + (lane&15)][kstep*32 + (lane>>4)*8 + j], j=0..7 (contiguous).
__global__ void prep_kernel(const float* __restrict__ h,
                            const float* __restrict__ W,
                            unsigned short* __restrict__ hb,
                            short8* __restrict__ Wfrag) {
  if (blockIdx.x < 1024) {
    constexpr int n4 = kNodes * kD / 4;  // 1.6M float4s
    int stride = 1024 * 256;
    for (int i = blockIdx.x * 256 + threadIdx.x; i < n4; i += stride) {
      float4 v = reinterpret_cast<const float4*>(h)[i];
      ushort4 o;
      o.x = f2bf(v.x); o.y = f2bf(v.y); o.z = f2bf(v.z); o.w = f2bf(v.w);
      reinterpret_cast<ushort4*>(hb)[i] = o;
    }
  } else {
    int s = (int)(blockIdx.x - 1024) * 256 + threadIdx.x;  // 0..2047
    int kstep = s >> 8;
    int ntile = (s >> 6) & 3;
    int ln    = s & 63;
    int n = ntile * 16 + (ln & 15);
    int k = kstep * 32 + (ln >> 4) * 8;
    const float* wp = W + n * kK + k;
    float4 w0 = *reinterpret_cast<const float4*>(wp);
    float4 w1 = *reinterpret_cast<const float4*>(wp + 4);
    Wfrag[s] = cvt8(w0, w1);
  }
}

// Main kernel: block = 256 threads = 4 waves. Grid-stride over tiles of 128
// edges (wave handles 32 edges = two 16-row A-subtiles sharing each B frag).
// W staged once per block into LDS (pure 16B copies), NO barriers in the loop.
template <bool BF16H>
__global__ __launch_bounds__(256, 4)
void edge_mlp_kernel(const unsigned short* __restrict__ hb,
                     const float* __restrict__ hf,
                     const short8* __restrict__ Wfrag,
                     const float* __restrict__ W,
                     const int* __restrict__ src,
                     const int* __restrict__ dst,
                     const float* __restrict__ b,
                     float* __restrict__ out) {
  __shared__ short8 Blds[2048];  // 32 KiB

  const int tid = threadIdx.x;

  if (BF16H) {
#pragma unroll
    for (int i = 0; i < 8; ++i) Blds[tid + i * 256] = Wfrag[tid + i * 256];
  } else {
    for (int s = tid; s < 2048; s += 256) {
      int kstep = s >> 8, ntile = (s >> 6) & 3, ln = s & 63;
      int n = ntile * 16 + (ln & 15);
      int k = kstep * 32 + (ln >> 4) * 8;
      const float* wp = W + n * kK + k;
      Blds[s] = cvt8(*reinterpret_cast<const float4*>(wp),
                     *reinterpret_cast<const float4*>(wp + 4));
    }
  }

  const int lane = tid & 63;
  const int wave = tid >> 6;
  const int rowA = lane & 15;   // edge-within-subtile / output col
  const int quad = lane >> 4;   // K sub-segment / output row group
  const int col  = rowA;

  float bv[4];
#pragma unroll
  for (int nt = 0; nt < 4; ++nt) bv[nt] = b[nt * 16 + col];

  __syncthreads();

  constexpr int nTiles = (kEdges + 127) / 128;  // 3907

  for (int t = blockIdx.x; t < nTiles; t += gridDim.x) {
    const long ebase = (long)t * 128 + (long)wave * 32;
    const long eA0 = ebase + rowA;
    const long eA1 = eA0 + 16;
    const int ec0 = (eA0 < kEdges) ? (int)eA0 : (kEdges - 1);
    const int ec1 = (eA1 < kEdges) ? (int)eA1 : (kEdges - 1);
    const int si0 = src[ec0], di0 = dst[ec0];
    const int si1 = src[ec1], di1 = dst[ec1];

    short8 a0[8], a1[8];
    if (BF16H) {
      const short8* ps0 = reinterpret_cast<const short8*>(hb + (size_t)si0 * kD);
      const short8* pd0 = reinterpret_cast<const short8*>(hb + (size_t)di0 * kD);
      const short8* ps1 = reinterpret_cast<const short8*>(hb + (size_t)si1 * kD);
      const short8* pd1 = reinterpret_cast<const short8*>(hb + (size_t)di1 * kD);
#pragma unroll
      for (int kstep = 0; kstep < 8; ++kstep) {
        // fragment offset in short8 units: kstep*4 + quad (per 128-elem row)
        a0[kstep] = (kstep < 4) ? ps0[kstep * 4 + quad] : pd0[(kstep - 4) * 4 + quad];
        a1[kstep] = (kstep < 4) ? ps1[kstep * 4 + quad] : pd1[(kstep - 4) * 4 + quad];
      }
    } else {
      const float* ps0 = hf + (size_t)si0 * kD;
      const float* pd0 = hf + (size_t)di0 * kD;
      const float* ps1 = hf + (size_t)si1 * kD;
      const float* pd1 = hf + (size_t)di1 * kD;
#pragma unroll
      for (int kstep = 0; kstep < 8; ++kstep) {
        int koff = kstep * 32 + quad * 8;
        const float* p0 = (kstep < 4) ? (ps0 + koff) : (pd0 + (koff - kD));
        const float* p1 = (kstep < 4) ? (ps1 + koff) : (pd1 + (koff - kD));
        a0[kstep] = cvt8(*reinterpret_cast<const float4*>(p0),
                         *reinterpret_cast<const float4*>(p0 + 4));
        a1[kstep] = cvt8(*reinterpret_cast<const float4*>(p1),
                         *reinterpret_cast<const float4*>(p1 + 4));
      }
    }

    floatx4 acc0[4], acc1[4];
#pragma unroll
    for (int nt = 0; nt < 4; ++nt) {
      acc0[nt] = (floatx4){0.f, 0.f, 0.f, 0.f};
      acc1[nt] = (floatx4){0.f, 0.f, 0.f, 0.f};
    }

    // Hot loop: 32 ds_read_b128, 64 MFMAs (each B frag feeds 2 subtiles)
#pragma unroll
    for (int kstep = 0; kstep < 8; ++kstep) {
#pragma unroll
      for (int nt = 0; nt < 4; ++nt) {
        short8 bfrag = Blds[(kstep * 4 + nt) * 64 + lane];
        acc0[nt] = __builtin_amdgcn_mfma_f32_16x16x32_bf16(a0[kstep], bfrag,
                                                           acc0[nt], 0, 0, 0);
        acc1[nt] = __builtin_amdgcn_mfma_f32_16x16x32_bf16(a1[kstep], bfrag,
                                                           acc1[nt], 0, 0, 0);
      }
    }

    // Epilogue: C/D layout col=lane&15, row=quad*4+reg  [m89/m91]
    const bool full = (ebase + 32) <= (long)kEdges;  // wave-uniform
    if (full) {
#pragma unroll
      for (int nt = 0; nt < 4; ++nt) {
#pragma unroll
        for (int r = 0; r < 4; ++r) {
          long r0 = ebase + quad * 4 + r;
          out[r0 * (long)kC + nt * 16 + col] = acc0[nt][r] + bv[nt];
          out[(r0 + 16) * (long)kC + nt * 16 + col] = acc1[nt][r] + bv[nt];
        }
      }
    } else {
#pragma unroll
      for (int nt = 0; nt < 4; ++nt) {
#pragma unroll
        for (int r = 0; r < 4; ++r) {
          long r0 = ebase + quad * 4 + r;
          if (r0 < kEdges)
            out[r0 * (long)kC + nt * 16 + col] = acc0[nt][r] + bv[nt];
          if (r0 + 16 < kEdges)
            out[(r0 + 16) * (long)kC + nt * 16 + col] = acc1[nt][r] + bv[nt];
        }
      }
    }
  }
}

extern "C" void kernel_launch(void* const* d_in, const int* in_sizes, int n_in,
                              void* d_out, int out_size, void* d_ws, size_t ws_size,
                              hipStream_t stream) {
  const float* h   = (const float*)d_in[0];
  const int*   src = (const int*)  d_in[1];
  const int*   dst = (const int*)  d_in[2];
  const float* W   = (const float*)d_in[3];
  const float* b   = (const float*)d_in[4];
  float*       out = (float*)d_out;

  const size_t hb_bytes = (size_t)kNodes * kD * sizeof(unsigned short);  // 12.8 MB
  const size_t wf_bytes = 2048 * sizeof(short8);                         // 32 KB

  if (ws_size >= hb_bytes + wf_bytes) {
    unsigned short* hb = (unsigned short*)d_ws;
    short8* Wfrag = (short8*)((char*)d_ws + hb_bytes);  // 16B-aligned (12.8e6 % 16 == 0)
    prep_kernel<<<1032, 256, 0, stream>>>(h, W, hb, Wfrag);
    edge_mlp_kernel<true><<<1024, 256, 0, stream>>>(hb, h, Wfrag, W, src, dst, b, out);
  } else {
    // Fallback: gather fp32 h directly, build W fragments in-kernel
    edge_mlp_kernel<false><<<1024, 256, 0, stream>>>(nullptr, h, nullptr, W, src, dst, b, out);
  }
}

// Round 3
// 190.549 us; speedup vs baseline: 1.4979x; 1.4979x over previous
//
#include <hip/hip_runtime.h>
#include <stdint.h>
#include <stddef.h>

constexpr int kNodes = 50000;
constexpr int kEdges = 500000;
constexpr int kD     = 128;   // per-half feature dim
constexpr int kC     = 64;    // out classes
constexpr int kK     = 256;   // W row length = 2*kD

typedef __attribute__((ext_vector_type(8))) short  short8;   // 8 x bf16
typedef __attribute__((ext_vector_type(4))) float  floatx4;  // MFMA C/D

__device__ __forceinline__ unsigned short f2bf(float f) {
  union { float f; unsigned u; } v; v.f = f;
  unsigned u = v.u;
  unsigned r = u + 0x7FFFu + ((u >> 16) & 1u);
  return (unsigned short)(r >> 16);
}

__device__ __forceinline__ float bf2f(short s) {
  union { unsigned u; float f; } v;
  v.u = ((unsigned)(unsigned short)s) << 16;
  return v.f;
}

__device__ __forceinline__ short8 cvt8(float4 a, float4 b) {
  short8 r;
  r[0] = (short)f2bf(a.x); r[1] = (short)f2bf(a.y);
  r[2] = (short)f2bf(a.z); r[3] = (short)f2bf(a.w);
  r[4] = (short)f2bf(b.x); r[5] = (short)f2bf(b.y);
  r[6] = (short)f2bf(b.z); r[7] = (short)f2bf(b.w);
  return r;
}

// ---------------------------------------------------------------------------
// Kernel 1: node-level GEMM.  P = h @ [W_u^T | W_v^T]  (50000 x 128),
// first 64 cols get +b, stored as bf16 into Pu / Pv tables in workspace.
// A (h) is read SEQUENTIALLY — no gather. Block = 256 thr = 4 waves;
// wave computes 16 rows x 128 cols via mfma_f32_16x16x32_bf16
// (4 K-steps x 8 N-tiles = 32 MFMAs). Grid = ceil(50000/64) = 782.
// ---------------------------------------------------------------------------
__global__ __launch_bounds__(256)
void node_gemm_kernel(const float* __restrict__ h,
                      const float* __restrict__ W,
                      const float* __restrict__ b,
                      unsigned short* __restrict__ Pu,
                      unsigned short* __restrict__ Pv) {
  __shared__ short8 Blds[2048];  // (kstep*8 + ntile)*64 + lane ; 32 KiB

  const int tid = threadIdx.x;

  // Stage W -> LDS in B-fragment order, cvt fp32->bf16 (only 782 blocks; cheap).
  for (int s = tid; s < 2048; s += 256) {
    int kstep = s >> 9;         // 0..3
    int ntile = (s >> 6) & 7;   // 0..7  (stacked col tile: 0..3 = W_u, 4..7 = W_v)
    int ln    = s & 63;
    int np = ntile * 16 + (ln & 15);     // stacked output col 0..127
    int k  = kstep * 32 + (ln >> 4) * 8; // 0..127
    int wc = (np < kC) ? np : (np - kC);
    int wk = (np < kC) ? k  : (k + kD);
    const float* wp = W + wc * kK + wk;
    Blds[s] = cvt8(*reinterpret_cast<const float4*>(wp),
                   *reinterpret_cast<const float4*>(wp + 4));
  }

  const int lane = tid & 63;
  const int wave = tid >> 6;
  const int rowA = lane & 15;
  const int quad = lane >> 4;
  const int col  = rowA;

  const int rowbase = blockIdx.x * 64 + wave * 16;
  const int n  = rowbase + rowA;
  const int nc = (n < kNodes) ? n : (kNodes - 1);   // clamp tail reads

  // A fragments: h row nc, fp32 -> bf16 in registers.
  short8 afrag[4];
#pragma unroll
  for (int kstep = 0; kstep < 4; ++kstep) {
    const float* ap = h + (size_t)nc * kD + kstep * 32 + quad * 8;
    afrag[kstep] = cvt8(*reinterpret_cast<const float4*>(ap),
                        *reinterpret_cast<const float4*>(ap + 4));
  }

  floatx4 acc[8];
#pragma unroll
  for (int nt = 0; nt < 8; ++nt) acc[nt] = (floatx4){0.f, 0.f, 0.f, 0.f};

  __syncthreads();

#pragma unroll
  for (int kstep = 0; kstep < 4; ++kstep) {
#pragma unroll
    for (int nt = 0; nt < 8; ++nt) {
      short8 bfrag = Blds[(kstep * 8 + nt) * 64 + lane];
      acc[nt] = __builtin_amdgcn_mfma_f32_16x16x32_bf16(afrag[kstep], bfrag,
                                                        acc[nt], 0, 0, 0);
    }
  }

  // Epilogue: C/D layout col=lane&15, row=quad*4+reg [m89/m91].
  // nt 0..3 -> Pu (+bias), nt 4..7 -> Pv.
#pragma unroll
  for (int nt = 0; nt < 4; ++nt) {
    float bv = b[nt * 16 + col];
#pragma unroll
    for (int r = 0; r < 4; ++r) {
      int n2 = rowbase + quad * 4 + r;
      if (n2 < kNodes)
        Pu[(size_t)n2 * kC + nt * 16 + col] = f2bf(acc[nt][r] + bv);
    }
  }
#pragma unroll
  for (int nt = 4; nt < 8; ++nt) {
#pragma unroll
    for (int r = 0; r < 4; ++r) {
      int n2 = rowbase + quad * 4 + r;
      if (n2 < kNodes)
        Pv[(size_t)n2 * kC + (nt - 4) * 16 + col] = f2bf(acc[nt][r]);
    }
  }
}

// ---------------------------------------------------------------------------
// Kernel 2: edge combine.  out[e,:] = f32(Pu[src[e],:]) + f32(Pv[dst[e],:]).
// 8 lanes per edge, each handling 8 cols (16 B bf16 gather x2, 32 B f32 store).
// Block = 256 thr -> 32 edges/pass, 4 passes -> 128 edges/block.
// Stores are perfectly coalesced (contiguous 8 KB per pass per block).
// ---------------------------------------------------------------------------
__global__ __launch_bounds__(256)
void edge_combine_kernel(const unsigned short* __restrict__ Pu,
                         const unsigned short* __restrict__ Pv,
                         const int* __restrict__ src,
                         const int* __restrict__ dst,
                         float* __restrict__ out) {
  const int tid = threadIdx.x;
  const int g   = tid & 7;    // col group: cols 8g..8g+7
  const int er  = tid >> 3;   // edge-within-pass 0..31
  const long base = (long)blockIdx.x * 128;

#pragma unroll
  for (int j = 0; j < 4; ++j) {
    long e = base + j * 32 + er;
    if (e < kEdges) {
      int s = src[e];
      int d = dst[e];
      short8 pu = *reinterpret_cast<const short8*>(Pu + (size_t)s * kC + g * 8);
      short8 pv = *reinterpret_cast<const short8*>(Pv + (size_t)d * kC + g * 8);
      float4 o0, o1;
      o0.x = bf2f(pu[0]) + bf2f(pv[0]);
      o0.y = bf2f(pu[1]) + bf2f(pv[1]);
      o0.z = bf2f(pu[2]) + bf2f(pv[2]);
      o0.w = bf2f(pu[3]) + bf2f(pv[3]);
      o1.x = bf2f(pu[4]) + bf2f(pv[4]);
      o1.y = bf2f(pu[5]) + bf2f(pv[5]);
      o1.z = bf2f(pu[6]) + bf2f(pv[6]);
      o1.w = bf2f(pu[7]) + bf2f(pv[7]);
      float* op = out + e * (long)kC + g * 8;
      *reinterpret_cast<float4*>(op)     = o0;
      *reinterpret_cast<float4*>(op + 4) = o1;
    }
  }
}

extern "C" void kernel_launch(void* const* d_in, const int* in_sizes, int n_in,
                              void* d_out, int out_size, void* d_ws, size_t ws_size,
                              hipStream_t stream) {
  const float* h   = (const float*)d_in[0];
  const int*   src = (const int*)  d_in[1];
  const int*   dst = (const int*)  d_in[2];
  const float* W   = (const float*)d_in[3];
  const float* b   = (const float*)d_in[4];
  float*       out = (float*)d_out;

  // Workspace: Pu (50000x64 bf16) | Pv (50000x64 bf16) = 12.8 MB total.
  // (Prior rounds prove ws_size >= 12.83 MB.)
  const size_t tbl = (size_t)kNodes * kC * sizeof(unsigned short);  // 6.4 MB
  unsigned short* Pu = (unsigned short*)d_ws;
  unsigned short* Pv = (unsigned short*)((char*)d_ws + tbl);        // 16B-aligned

  const int gemm_grid = (kNodes + 63) / 64;     // 782
  const int edge_grid = (kEdges + 127) / 128;   // 3907

  node_gemm_kernel<<<gemm_grid, 256, 0, stream>>>(h, W, b, Pu, Pv);
  edge_combine_kernel<<<edge_grid, 256, 0, stream>>>(Pu, Pv, src, dst, out);
}

// Round 4
// 187.829 us; speedup vs baseline: 1.5196x; 1.0145x over previous
//
#include <hip/hip_runtime.h>
#include <stdint.h>
#include <stddef.h>

constexpr int kNodes = 50000;
constexpr int kEdges = 500000;
constexpr int kD     = 128;   // per-half feature dim
constexpr int kC     = 64;    // out classes
constexpr int kK     = 256;   // W row length = 2*kD

typedef __attribute__((ext_vector_type(8))) short  short8;   // 8 x bf16
typedef __attribute__((ext_vector_type(4))) float  floatx4;  // MFMA C/D

__device__ __forceinline__ unsigned short f2bf(float f) {
  union { float f; unsigned u; } v; v.f = f;
  unsigned u = v.u;
  unsigned r = u + 0x7FFFu + ((u >> 16) & 1u);
  return (unsigned short)(r >> 16);
}

__device__ __forceinline__ float bf2f(short s) {
  union { unsigned u; float f; } v;
  v.u = ((unsigned)(unsigned short)s) << 16;
  return v.f;
}

__device__ __forceinline__ short8 cvt8(float4 a, float4 b) {
  short8 r;
  r[0] = (short)f2bf(a.x); r[1] = (short)f2bf(a.y);
  r[2] = (short)f2bf(a.z); r[3] = (short)f2bf(a.w);
  r[4] = (short)f2bf(b.x); r[5] = (short)f2bf(b.y);
  r[6] = (short)f2bf(b.z); r[7] = (short)f2bf(b.w);
  return r;
}

// ---------------------------------------------------------------------------
// Kernel 1: node GEMM.  P = h @ [W_u^T | W_v^T] (50000 x 128); first 64 cols
// get +b. Stored bf16 into Pu / Pv. h read sequentially (no gather).
// Block = 256 thr = 4 waves; each block does 128 rows (wave: 32 rows = two
// 16-row subtiles sharing every B fragment -> 64 MFMAs/wave). Grid = 391.
// ---------------------------------------------------------------------------
__global__ __launch_bounds__(256)
void node_gemm_kernel(const float* __restrict__ h,
                      const float* __restrict__ W,
                      const float* __restrict__ b,
                      unsigned short* __restrict__ Pu,
                      unsigned short* __restrict__ Pv) {
  __shared__ short8 Blds[2048];  // (kstep*8 + ntile)*64 + lane ; 32 KiB

  const int tid = threadIdx.x;

  // Stage W -> LDS in B-fragment order (stacked cols: 0..63 = W_u, 64..127 = W_v)
  for (int s = tid; s < 2048; s += 256) {
    int kstep = s >> 9;         // 0..3
    int ntile = (s >> 6) & 7;   // 0..7
    int ln    = s & 63;
    int np = ntile * 16 + (ln & 15);
    int k  = kstep * 32 + (ln >> 4) * 8;
    int wc = (np < kC) ? np : (np - kC);
    int wk = (np < kC) ? k  : (k + kD);
    const float* wp = W + wc * kK + wk;
    Blds[s] = cvt8(*reinterpret_cast<const float4*>(wp),
                   *reinterpret_cast<const float4*>(wp + 4));
  }

  const int lane = tid & 63;
  const int wave = tid >> 6;
  const int rowA = lane & 15;
  const int quad = lane >> 4;
  const int col  = rowA;

  const int rowbase = blockIdx.x * 128 + wave * 32;
  int n0 = rowbase + rowA;       if (n0 >= kNodes) n0 = kNodes - 1;
  int n1 = rowbase + 16 + rowA;  if (n1 >= kNodes) n1 = kNodes - 1;

  short8 a0[4], a1[4];
#pragma unroll
  for (int kstep = 0; kstep < 4; ++kstep) {
    const float* p0 = h + (size_t)n0 * kD + kstep * 32 + quad * 8;
    const float* p1 = h + (size_t)n1 * kD + kstep * 32 + quad * 8;
    a0[kstep] = cvt8(*reinterpret_cast<const float4*>(p0),
                     *reinterpret_cast<const float4*>(p0 + 4));
    a1[kstep] = cvt8(*reinterpret_cast<const float4*>(p1),
                     *reinterpret_cast<const float4*>(p1 + 4));
  }

  floatx4 acc0[8], acc1[8];
#pragma unroll
  for (int nt = 0; nt < 8; ++nt) {
    acc0[nt] = (floatx4){0.f, 0.f, 0.f, 0.f};
    acc1[nt] = (floatx4){0.f, 0.f, 0.f, 0.f};
  }

  __syncthreads();

#pragma unroll
  for (int kstep = 0; kstep < 4; ++kstep) {
#pragma unroll
    for (int nt = 0; nt < 8; ++nt) {
      short8 bfrag = Blds[(kstep * 8 + nt) * 64 + lane];
      acc0[nt] = __builtin_amdgcn_mfma_f32_16x16x32_bf16(a0[kstep], bfrag,
                                                         acc0[nt], 0, 0, 0);
      acc1[nt] = __builtin_amdgcn_mfma_f32_16x16x32_bf16(a1[kstep], bfrag,
                                                         acc1[nt], 0, 0, 0);
    }
  }

  // Epilogue: C/D layout col=lane&15, row=quad*4+reg [m89/m91].
  const bool full = (rowbase + 32) <= kNodes;  // wave-uniform
#pragma unroll
  for (int nt = 0; nt < 4; ++nt) {
    float bv = b[nt * 16 + col];
#pragma unroll
    for (int r = 0; r < 4; ++r) {
      int ra = rowbase + quad * 4 + r;
      int rb = ra + 16;
      if (full || ra < kNodes)
        Pu[(size_t)ra * kC + nt * 16 + col] = f2bf(acc0[nt][r] + bv);
      if (full || rb < kNodes)
        Pu[(size_t)rb * kC + nt * 16 + col] = f2bf(acc1[nt][r] + bv);
    }
  }
#pragma unroll
  for (int nt = 4; nt < 8; ++nt) {
#pragma unroll
    for (int r = 0; r < 4; ++r) {
      int ra = rowbase + quad * 4 + r;
      int rb = ra + 16;
      if (full || ra < kNodes)
        Pv[(size_t)ra * kC + (nt - 4) * 16 + col] = f2bf(acc0[nt][r]);
      if (full || rb < kNodes)
        Pv[(size_t)rb * kC + (nt - 4) * 16 + col] = f2bf(acc1[nt][r]);
    }
  }
}

// ---------------------------------------------------------------------------
// Kernel 2: edge combine.  out[e,:] = f32(Pu[src[e],:]) + f32(Pv[dst[e],:]).
// 8 lanes/edge (16 B bf16 gather x2 per lane, 32 B f32 store). 256 edges per
// block in 8 passes; ALL 16 gathers issued before any use (latency hiding).
// Stores: each wave writes 8 consecutive edges x 256 B = 2 KB contiguous.
// ---------------------------------------------------------------------------
__global__ __launch_bounds__(256)
void edge_combine_kernel(const unsigned short* __restrict__ Pu,
                         const unsigned short* __restrict__ Pv,
                         const int* __restrict__ src,
                         const int* __restrict__ dst,
                         float* __restrict__ out) {
  const int tid = threadIdx.x;
  const int g   = tid & 7;    // col group: cols 8g..8g+7
  const int er  = tid >> 3;   // edge-within-pass 0..31
  const long base = (long)blockIdx.x * 256;
  const bool full = (base + 256) <= (long)kEdges;

  if (full) {
    int si[8], di[8];
#pragma unroll
    for (int j = 0; j < 8; ++j) {
      long e = base + j * 32 + er;
      si[j] = src[e];
      di[j] = dst[e];
    }
    short8 pu[8], pv[8];
#pragma unroll
    for (int j = 0; j < 8; ++j) {
      pu[j] = *reinterpret_cast<const short8*>(Pu + (size_t)si[j] * kC + g * 8);
      pv[j] = *reinterpret_cast<const short8*>(Pv + (size_t)di[j] * kC + g * 8);
    }
#pragma unroll
    for (int j = 0; j < 8; ++j) {
      float4 o0, o1;
      o0.x = bf2f(pu[j][0]) + bf2f(pv[j][0]);
      o0.y = bf2f(pu[j][1]) + bf2f(pv[j][1]);
      o0.z = bf2f(pu[j][2]) + bf2f(pv[j][2]);
      o0.w = bf2f(pu[j][3]) + bf2f(pv[j][3]);
      o1.x = bf2f(pu[j][4]) + bf2f(pv[j][4]);
      o1.y = bf2f(pu[j][5]) + bf2f(pv[j][5]);
      o1.z = bf2f(pu[j][6]) + bf2f(pv[j][6]);
      o1.w = bf2f(pu[j][7]) + bf2f(pv[j][7]);
      float* op = out + (base + j * 32 + er) * (long)kC + g * 8;
      *reinterpret_cast<float4*>(op)     = o0;
      *reinterpret_cast<float4*>(op + 4) = o1;
    }
  } else {
#pragma unroll
    for (int j = 0; j < 8; ++j) {
      long e = base + j * 32 + er;
      if (e < kEdges) {
        int s = src[e];
        int d = dst[e];
        short8 pu = *reinterpret_cast<const short8*>(Pu + (size_t)s * kC + g * 8);
        short8 pv = *reinterpret_cast<const short8*>(Pv + (size_t)d * kC + g * 8);
        float4 o0, o1;
        o0.x = bf2f(pu[0]) + bf2f(pv[0]);
        o0.y = bf2f(pu[1]) + bf2f(pv[1]);
        o0.z = bf2f(pu[2]) + bf2f(pv[2]);
        o0.w = bf2f(pu[3]) + bf2f(pv[3]);
        o1.x = bf2f(pu[4]) + bf2f(pv[4]);
        o1.y = bf2f(pu[5]) + bf2f(pv[5]);
        o1.z = bf2f(pu[6]) + bf2f(pv[6]);
        o1.w = bf2f(pu[7]) + bf2f(pv[7]);
        float* op = out + e * (long)kC + g * 8;
        *reinterpret_cast<float4*>(op)     = o0;
        *reinterpret_cast<float4*>(op + 4) = o1;
      }
    }
  }
}

extern "C" void kernel_launch(void* const* d_in, const int* in_sizes, int n_in,
                              void* d_out, int out_size, void* d_ws, size_t ws_size,
                              hipStream_t stream) {
  const float* h   = (const float*)d_in[0];
  const int*   src = (const int*)  d_in[1];
  const int*   dst = (const int*)  d_in[2];
  const float* W   = (const float*)d_in[3];
  const float* b   = (const float*)d_in[4];
  float*       out = (float*)d_out;

  // Workspace: Pu (50000x64 bf16) | Pv (50000x64 bf16) = 12.8 MB total.
  const size_t tbl = (size_t)kNodes * kC * sizeof(unsigned short);  // 6.4 MB
  unsigned short* Pu = (unsigned short*)d_ws;
  unsigned short* Pv = (unsigned short*)((char*)d_ws + tbl);        // 16B-aligned

  const int gemm_grid = (kNodes + 127) / 128;   // 391
  const int edge_grid = (kEdges + 255) / 256;   // 1954

  node_gemm_kernel<<<gemm_grid, 256, 0, stream>>>(h, W, b, Pu, Pv);
  edge_combine_kernel<<<edge_grid, 256, 0, stream>>>(Pu, Pv, src, dst, out);
}